// Round 1
// baseline (2279.496 us; speedup 1.0000x reference)
//
#include <hip/hip_runtime.h>

typedef unsigned short u16;
typedef unsigned int u32;
typedef __attribute__((ext_vector_type(8))) short short8;
typedef __attribute__((ext_vector_type(8))) u16 u16x8;
typedef __attribute__((ext_vector_type(4))) float f32x4;

#define N_NODES 5000
#define NP 5120
#define BTOT 96
#define J_DIM 6144
#define TT 24
#define KNEG 20

__device__ __forceinline__ float b2f(u16 u){ union{u32 i; float f;} x; x.i = ((u32)u)<<16; return x.f; }
__device__ __forceinline__ u16 f2b(float f){ union{float fl; u32 i;} x; x.fl = f; u32 r = (x.i + 0x7fffu + ((x.i>>16)&1u))>>16; return (u16)r; }

// ---------------- tiny precompute: u0,u1,u2,bias1, cA,cB,cC -----------------
__global__ void k_prep(const float* __restrict__ Ws, const float* __restrict__ bs,
                       const float* __restrict__ W1, const float* __restrict__ b1,
                       const float* __restrict__ W2, float* __restrict__ consts)
{
  int d = threadIdx.x; // 64 threads
  float u0=0.f,u1=0.f,u2=0.f,bb=0.f;
  for (int c=0;c<64;c++){
    float w = Ws[c];
    float a = W1[c*64+d], b_ = W1[(64+c)*64+d], cw = W1[(128+c)*64+d];
    u0 += w*a; u1 += w*b_; u2 += w*cw;
    bb += bs[c]*(a+b_+cw);
  }
  bb += b1[d];
  consts[d]=u0; consts[64+d]=u1; consts[128+d]=u2; consts[192+d]=bb;
  __shared__ float rb[64];
  rb[d] = fmaxf(bb, 0.f);
  __syncthreads();
  float cA=0.f,cB=0.f,cC=0.f;
  for (int c=0;c<64;c++){
    float r = rb[c];
    cA += r*W2[c*64+d]; cB += r*W2[(64+c)*64+d]; cC += r*W2[(128+c)*64+d];
  }
  consts[256+d]=cA; consts[320+d]=cB; consts[384+d]=cC;
}

// ---------------- degrees ----------------
__global__ __launch_bounds__(256) void k_rowsum(const float* __restrict__ adj,
    float* __restrict__ degr, float* __restrict__ invr)
{
  __shared__ float red[256];
  int m = blockIdx.x;
  float s = 0.f;
  if (m < N_NODES)
    for (int n = threadIdx.x; n < N_NODES; n += 256) s += adj[(size_t)m*N_NODES + n];
  red[threadIdx.x] = s;
  __syncthreads();
  for (int o=128;o;o>>=1){ if ((int)threadIdx.x < o) red[threadIdx.x] += red[threadIdx.x+o]; __syncthreads(); }
  if (threadIdx.x == 0){
    float dv = red[0];
    degr[m] = (m < N_NODES) ? dv : 0.f;
    invr[m] = (m < N_NODES && dv > 0.f) ? 1.f/dv : 0.f;
  }
}

__global__ __launch_bounds__(256) void k_colsum(const float* __restrict__ adj, float* __restrict__ degc)
{
  int c = blockIdx.x*256 + threadIdx.x;
  if (c >= N_NODES) return;
  int r0 = blockIdx.y * 125;
  float s = 0.f;
  for (int r = r0; r < r0+125; r++) s += adj[(size_t)r*N_NODES + c];
  atomicAdd(&degc[c], s);
}

__global__ void k_invc(const float* __restrict__ degc, float* __restrict__ invc){
  int c = blockIdx.x*256 + threadIdx.x;
  if (c < NP){ float dv = degc[c]; invc[c] = (dv > 0.f) ? 1.f/dv : 0.f; }
}

// ---------------- adj -> bf16 (A and A^T), zero-padded to 5120 ----------------
__global__ __launch_bounds__(256) void k_convT(const float* __restrict__ adj,
    u16* __restrict__ abf, u16* __restrict__ atbf)
{
  __shared__ u16 tile[64][65];
  const int tid = threadIdx.x;
  const int c = tid & 63;
  const int r0 = (tid >> 6) * 16;
  const int bx = blockIdx.x, by = blockIdx.y;
  #pragma unroll
  for (int i=0;i<16;i++){
    int r = r0 + i;
    int gm = by*64 + r, gk = bx*64 + c;
    float v = (gm < N_NODES && gk < N_NODES) ? adj[(size_t)gm*N_NODES + gk] : 0.f;
    u16 u = f2b(v);
    abf[(size_t)(by*64+r)*NP + bx*64 + c] = u;
    tile[r][c] = u;
  }
  __syncthreads();
  #pragma unroll
  for (int i=0;i<16;i++){
    int r = r0 + i;
    atbf[(size_t)(bx*64+r)*NP + by*64 + c] = tile[c][r];
  }
}

// ---------------- x transpose [96][5000] -> [5120][96] ----------------
__global__ void k_xT(const float* __restrict__ x, float* __restrict__ xT){
  int n = blockIdx.x*256 + threadIdx.x;
  if (n >= NP) return;
  for (int bt=0; bt<BTOT; bt++)
    xT[(size_t)n*BTOT + bt] = (n < N_NODES) ? x[(size_t)bt*N_NODES + n] : 0.f;
}

// ---------------- y = M(bf16) @ xT : [5120x5120]x[5120x96] ----------------
__global__ __launch_bounds__(256) void k_ygemm(const u16* __restrict__ M,
    const float* __restrict__ xT, float* __restrict__ yout)
{
  int ml = threadIdx.x & 63, btg = threadIdx.x >> 6;
  int m = blockIdx.x*64 + ml;
  int k0 = blockIdx.y*640;
  float acc[24];
  #pragma unroll
  for (int j=0;j<24;j++) acc[j]=0.f;
  for (int k8=0; k8<80; k8++){
    u16x8 av = *(const u16x8*)(M + (size_t)m*NP + k0 + k8*8);
    #pragma unroll
    for (int e=0;e<8;e++){
      float a = b2f(av[e]);
      const float* xr = xT + (size_t)(k0 + k8*8 + e)*BTOT + btg*24;
      #pragma unroll
      for (int j=0;j<24;j++) acc[j] += a * xr[j];
    }
  }
  if (m < N_NODES){
    #pragma unroll
    for (int j=0;j<24;j++) atomicAdd(&yout[(size_t)(btg*24+j)*N_NODES + m], acc[j]);
  }
}

// ---------------- layer-1 combine -> H1^T [j=bt*64+d][n] bf16 ----------------
__global__ void k_h1(const float* __restrict__ x, const float* __restrict__ y1,
    const float* __restrict__ y2, const float* __restrict__ invr, const float* __restrict__ invc,
    const float* __restrict__ consts, u16* __restrict__ h1t)
{
  int n = blockIdx.x*256 + threadIdx.x;
  int j = blockIdx.y;
  int d = j & 63, bt = j >> 6;
  float v = 0.f;
  if (n < N_NODES){
    float u0 = consts[d], u1 = consts[64+d], u2 = consts[128+d], bb = consts[192+d];
    size_t off = (size_t)bt*N_NODES + n;
    v = x[off]*u0 + invr[n]*y1[off]*u1 + invc[n]*y2[off]*u2 + bb;
    v = fmaxf(v, 0.f);
  }
  if (n < NP) h1t[(size_t)j*NP + n] = f2b(v);
}

// ---------------- big GEMM: C[m][j] = scale[m] * sum_k A[m][k]*Bt[j][k] ----------------
__global__ __launch_bounds__(256) void k_gemm(
    const u16* __restrict__ A, const u16* __restrict__ Bt,
    u16* __restrict__ C, const float* __restrict__ rowscale)
{
  __shared__ __align__(16) u16 lA[128*32];
  __shared__ __align__(16) u16 lB[128*32];
  const int tid = threadIdx.x;
  const int lane = tid & 63;
  const int wv = tid >> 6;
  const int wm = (wv >> 1) * 64;
  const int wj = (wv & 1) * 64;
  const int m0 = blockIdx.x * 128;
  const int j0 = blockIdx.y * 128;

  f32x4 acc[4][4] = {};

  const u16* gA = A + (size_t)(m0 + (tid>>2)) * NP + (tid&3)*8;
  const u16* gB = Bt + (size_t)(j0 + (tid>>2)) * NP + (tid&3)*8;
  char* lAb = (char*)lA + wv*1024;
  char* lBb = (char*)lB + wv*1024;

  for (int k0 = 0; k0 < NP; k0 += 32) {
    __builtin_amdgcn_global_load_lds((const __attribute__((address_space(1))) void*)(gA + k0),
        (__attribute__((address_space(3))) void*)(lAb), 16, 0, 0);
    __builtin_amdgcn_global_load_lds((const __attribute__((address_space(1))) void*)(gA + (size_t)64*NP + k0),
        (__attribute__((address_space(3))) void*)(lAb + 4096), 16, 0, 0);
    __builtin_amdgcn_global_load_lds((const __attribute__((address_space(1))) void*)(gB + k0),
        (__attribute__((address_space(3))) void*)(lBb), 16, 0, 0);
    __builtin_amdgcn_global_load_lds((const __attribute__((address_space(1))) void*)(gB + (size_t)64*NP + k0),
        (__attribute__((address_space(3))) void*)(lBb + 4096), 16, 0, 0);
    __syncthreads();
    short8 af[4], bfv[4];
    const int kb = (lane >> 4) * 8;
    #pragma unroll
    for (int i=0;i<4;i++){
      af[i]  = *(const short8*)(lA + (wm + i*16 + (lane&15))*32 + kb);
      bfv[i] = *(const short8*)(lB + (wj + i*16 + (lane&15))*32 + kb);
    }
    #pragma unroll
    for (int i=0;i<4;i++){
      #pragma unroll
      for (int j=0;j<4;j++)
        acc[i][j] = __builtin_amdgcn_mfma_f32_16x16x32_bf16(af[i], bfv[j], acc[i][j], 0,0,0);
    }
    __syncthreads();
  }
  #pragma unroll
  for (int i=0;i<4;i++){
    #pragma unroll
    for (int r=0;r<4;r++){
      int row = m0 + wm + i*16 + (lane>>4)*4 + r;
      float sc = rowscale[row];
      #pragma unroll
      for (int j=0;j<4;j++){
        int col = j0 + wj + j*16 + (lane&15);
        C[(size_t)row*J_DIM + col] = f2b(acc[i][j][r] * sc);
      }
    }
  }
}

// ---------------- layer-2 channel matmul -> hori [bt][n][d] bf16 ----------------
__global__ __launch_bounds__(256) void k_combine(const u16* __restrict__ h1t,
  const u16* __restrict__ P, const u16* __restrict__ Q,
  const float* __restrict__ W2, const float* __restrict__ b2, u16* __restrict__ hori)
{
  __shared__ __align__(16) u16 hL[64*64];
  __shared__ u16 pL[64*64];
  __shared__ u16 qL[64*64];
  __shared__ __align__(16) u16 w2L[192*64];
  const int tid = threadIdx.x;
  const int n0 = blockIdx.x * 64;
  const int bt = blockIdx.y;

  for (int i = tid; i < 192*64; i += 256) w2L[i] = f2b(W2[i]);

  #pragma unroll
  for (int it=0; it<2; it++){
    int idx = it*256 + tid;
    int r = idx >> 3, ch = idx & 7;
    u16x8 hv = *(const u16x8*)(h1t + (size_t)(bt*64 + r)*NP + n0 + ch*8);
    *(u16x8*)(hL + r*64 + ch*8) = hv;
    u16x8 pv = *(const u16x8*)(P + (size_t)(n0 + r)*J_DIM + bt*64 + ch*8);
    u16x8 qv = *(const u16x8*)(Q + (size_t)(n0 + r)*J_DIM + bt*64 + ch*8);
    #pragma unroll
    for (int e=0;e<8;e++){
      pL[(ch*8+e)*64 + r] = pv[e];
      qL[(ch*8+e)*64 + r] = qv[e];
    }
  }
  __syncthreads();

  const int n = tid & 63, dbase = (tid >> 6) * 16;
  float acc[16];
  #pragma unroll
  for (int e=0;e<16;e++) acc[e]=0.f;
  for (int c=0;c<64;c++){
    float hv = b2f(hL[c*64+n]);
    float pv = b2f(pL[c*64+n]);
    float qv = b2f(qL[c*64+n]);
    const u16x8 wa0 = *(const u16x8*)(w2L + c*64 + dbase);
    const u16x8 wa1 = *(const u16x8*)(w2L + c*64 + dbase + 8);
    const u16x8 wb0 = *(const u16x8*)(w2L + (64+c)*64 + dbase);
    const u16x8 wb1 = *(const u16x8*)(w2L + (64+c)*64 + dbase + 8);
    const u16x8 wc0 = *(const u16x8*)(w2L + (128+c)*64 + dbase);
    const u16x8 wc1 = *(const u16x8*)(w2L + (128+c)*64 + dbase + 8);
    #pragma unroll
    for (int e=0;e<8;e++){
      acc[e]   += hv*b2f(wa0[e]) + pv*b2f(wb0[e]) + qv*b2f(wc0[e]);
      acc[8+e] += hv*b2f(wa1[e]) + pv*b2f(wb1[e]) + qv*b2f(wc1[e]);
    }
  }
  int gn = n0 + n;
  if (gn < N_NODES){
    u16x8 o0, o1;
    #pragma unroll
    for (int e=0;e<8;e++){
      o0[e] = f2b(acc[e]   + b2[dbase+e]);
      o1[e] = f2b(acc[8+e] + b2[dbase+8+e]);
    }
    u16* dst = hori + ((size_t)bt*N_NODES + gn)*64 + dbase;
    *(u16x8*)(dst) = o0;
    *(u16x8*)(dst+8) = o1;
  }
}

// ---------------- imputation head ----------------
__global__ __launch_bounds__(256) void k_head(const u16* __restrict__ hori,
  const float* __restrict__ Wf1, const float* __restrict__ bf1,
  const float* __restrict__ Wf2, const float* __restrict__ bf2, float* __restrict__ y)
{
  __shared__ float w1L[64*33];
  __shared__ float b1L[32];
  __shared__ float w2Ls[32];
  const int tid = threadIdx.x;
  for (int i = tid; i < 2048; i += 256) w1L[(i>>5)*33 + (i&31)] = Wf1[i];
  if (tid < 32){ b1L[tid] = bf1[tid]; w2Ls[tid] = Wf2[tid]; }
  __syncthreads();
  const int q = tid & 3;
  size_t pos = (size_t)blockIdx.x*64 + (tid>>2);
  const u16x8 a0 = *(const u16x8*)(hori + pos*64 + q*16);
  const u16x8 a1 = *(const u16x8*)(hori + pos*64 + q*16 + 8);
  float h[16];
  #pragma unroll
  for (int e=0;e<8;e++){ h[e]=b2f(a0[e]); h[8+e]=b2f(a1[e]); }
  float yacc = 0.f;
  #pragma unroll
  for (int jj=0; jj<32; jj++){
    float s = 0.f;
    #pragma unroll
    for (int dl=0; dl<16; dl++) s += h[dl]*w1L[(q*16+dl)*33 + jj];
    s += __shfl_xor(s, 1);
    s += __shfl_xor(s, 2);
    s += b1L[jj];
    yacc += fmaxf(s, 0.f)*w2Ls[jj];
  }
  if (q == 0) y[pos] = yacc + bf2[0];
}

// ---------------- InfoNCE loss ----------------
__global__ __launch_bounds__(256) void k_loss(const u16* __restrict__ hori,
  const int* __restrict__ missing, const int* __restrict__ posi, const int* __restrict__ negi,
  const float* __restrict__ degr, const float* __restrict__ degc,
  const float* __restrict__ consts, const float* __restrict__ b2, float* __restrict__ out)
{
  const int lane = threadIdx.x & 63;
  const int wv = threadIdx.x >> 6;
  const int wg = blockIdx.x*4 + wv;   // 0..24575
  const int m = wg & 255;
  const int bt = wg >> 8;
  const int t_ = bt % TT;
  const float cAv = consts[256+lane], cBv = consts[320+lane], cCv = consts[384+lane], b2v = b2[lane];

  int na = missing[m];
  float va = b2f(hori[((size_t)bt*N_NODES + na)*64 + lane]);
  float ss = va*va;
  #pragma unroll
  for (int o=32;o;o>>=1) ss += __shfl_xor(ss, o);
  va /= fmaxf(sqrtf(ss), 1e-8f);

  float l0 = 0.f, mx, se;
  {
    int node = posi[m];
    float v;
    if (t_ >= 4) v = b2f(hori[((size_t)bt*N_NODES + node)*64 + lane]);
    else {
      float r1 = (degr[node] > 0.f) ? 1.f : 0.f;
      float r2 = (degc[node] > 0.f) ? 1.f : 0.f;
      v = cAv + r1*cBv + r2*cCv + b2v;
    }
    float s2 = v*v;
    #pragma unroll
    for (int o=32;o;o>>=1) s2 += __shfl_xor(s2, o);
    v /= fmaxf(sqrtf(s2), 1e-8f);
    float dp = va*v;
    #pragma unroll
    for (int o=32;o;o>>=1) dp += __shfl_xor(dp, o);
    l0 = dp * 2.f;   // /TEMP, TEMP=0.5
  }
  mx = l0; se = 1.f;
  for (int k=0;k<KNEG;k++){
    int node = negi[m*KNEG + k];
    float v;
    if (t_ >= 4) v = b2f(hori[((size_t)bt*N_NODES + node)*64 + lane]);
    else {
      float r1 = (degr[node] > 0.f) ? 1.f : 0.f;
      float r2 = (degc[node] > 0.f) ? 1.f : 0.f;
      v = cAv + r1*cBv + r2*cCv + b2v;
    }
    float s2 = v*v;
    #pragma unroll
    for (int o=32;o;o>>=1) s2 += __shfl_xor(s2, o);
    v /= fmaxf(sqrtf(s2), 1e-8f);
    float dp = va*v;
    #pragma unroll
    for (int o=32;o;o>>=1) dp += __shfl_xor(dp, o);
    float lk = dp * 2.f;
    if (lk > mx){ se = se*expf(mx-lk) + 1.f; mx = lk; }
    else se += expf(lk-mx);
  }
  float term = logf(se) + mx - l0;
  __shared__ float red[4];
  if (lane == 0) red[wv] = term;
  __syncthreads();
  if (threadIdx.x == 0)
    atomicAdd(out + 480000, (red[0]+red[1]+red[2]+red[3]) * (1.f/24576.f));
}

extern "C" void kernel_launch(void* const* d_in, const int* in_sizes, int n_in,
                              void* d_out, int out_size, void* d_ws, size_t ws_size,
                              hipStream_t stream)
{
  const float* x   = (const float*)d_in[0];
  const float* adj = (const float*)d_in[1];
  const float* Ws  = (const float*)d_in[2];
  const float* bs  = (const float*)d_in[3];
  const float* W1  = (const float*)d_in[4];
  const float* b1  = (const float*)d_in[5];
  const float* W2  = (const float*)d_in[6];
  const float* b2  = (const float*)d_in[7];
  const float* Wf1 = (const float*)d_in[8];
  const float* bf1 = (const float*)d_in[9];
  const float* Wf2 = (const float*)d_in[10];
  const float* bf2 = (const float*)d_in[11];
  const int* missing = (const int*)d_in[12];
  const int* posi    = (const int*)d_in[13];
  const int* negi    = (const int*)d_in[14];
  float* out = (float*)d_out;

  char* w = (char*)d_ws;
  size_t o = 0;
  auto alloc = [&](size_t bytes){ size_t r = o; o += (bytes + 255) & ~(size_t)255; return r; };
  u16* abf   = (u16*)(w + alloc((size_t)NP*NP*2));
  u16* atbf  = (u16*)(w + alloc((size_t)NP*NP*2));
  u16* h1t   = (u16*)(w + alloc((size_t)J_DIM*NP*2));
  u16* Pb    = (u16*)(w + alloc((size_t)NP*J_DIM*2));
  u16* Qb    = (u16*)(w + alloc((size_t)NP*J_DIM*2));
  u16* hori  = (u16*)(w + alloc((size_t)BTOT*N_NODES*64*2));
  float* y1  = (float*)(w + alloc(1920000));
  float* y2  = (float*)(w + alloc(1920000));
  float* degc= (float*)(w + alloc(20480));
  float* xT  = (float*)(w + alloc((size_t)NP*BTOT*4));
  float* invr= (float*)(w + alloc(20480));
  float* invc= (float*)(w + alloc(20480));
  float* degr= (float*)(w + alloc(20480));
  float* consts = (float*)(w + alloc(2048));

  // y1, y2, degc are contiguous and atomically accumulated -> zero each call
  hipMemsetAsync(y1, 0, 1920000 + 1920000 + 20480, stream);
  hipMemsetAsync(out + 480000, 0, 4, stream);   // loss accumulator

  k_prep<<<1, 64, 0, stream>>>(Ws, bs, W1, b1, W2, consts);
  k_rowsum<<<NP, 256, 0, stream>>>(adj, degr, invr);
  k_colsum<<<dim3(20,40), 256, 0, stream>>>(adj, degc);
  k_invc<<<20, 256, 0, stream>>>(degc, invc);
  k_convT<<<dim3(80,80), 256, 0, stream>>>(adj, abf, atbf);
  k_xT<<<20, 256, 0, stream>>>(x, xT);
  k_ygemm<<<dim3(79,8), 256, 0, stream>>>(abf, xT, y1);
  k_ygemm<<<dim3(79,8), 256, 0, stream>>>(atbf, xT, y2);
  k_h1<<<dim3(20,6144), 256, 0, stream>>>(x, y1, y2, invr, invc, consts, h1t);
  k_gemm<<<dim3(40,48), 256, 0, stream>>>(abf, h1t, Pb, invr);
  k_gemm<<<dim3(40,48), 256, 0, stream>>>(atbf, h1t, Qb, invc);
  k_combine<<<dim3(79,96), 256, 0, stream>>>(h1t, Pb, Qb, W2, b2, hori);
  k_head<<<7500, 256, 0, stream>>>(hori, Wf1, bf1, Wf2, bf2, out);
  k_loss<<<6144, 256, 0, stream>>>(hori, missing, posi, negi, degr, degc, consts, b2, out);
}

// Round 2
// 1253.977 us; speedup vs baseline: 1.8178x; 1.8178x over previous
//
#include <hip/hip_runtime.h>

typedef unsigned short u16;
typedef unsigned int u32;
typedef __attribute__((ext_vector_type(8))) short short8;
typedef __attribute__((ext_vector_type(8))) u16 u16x8;
typedef __attribute__((ext_vector_type(4))) float f32x4;

#define N_NODES 5000
#define NP 5120
#define BTOT 96
#define J_DIM 6144
#define TT 24
#define KNEG 20

__device__ __forceinline__ float b2f(u16 u){ union{u32 i; float f;} x; x.i = ((u32)u)<<16; return x.f; }
__device__ __forceinline__ u16 f2b(float f){ union{float fl; u32 i;} x; x.fl = f; u32 r = (x.i + 0x7fffu + ((x.i>>16)&1u))>>16; return (u16)r; }

#define GLOAD16(g, l) __builtin_amdgcn_global_load_lds((const __attribute__((address_space(1))) void*)(g), (__attribute__((address_space(3))) void*)(l), 16, 0, 0)

// ---------------- tiny precompute: u0,u1,u2,bias1, cA,cB,cC, W2^T -----------------
__global__ void k_prep(const float* __restrict__ Ws, const float* __restrict__ bs,
                       const float* __restrict__ W1, const float* __restrict__ b1,
                       const float* __restrict__ W2, float* __restrict__ consts,
                       u16* __restrict__ w2t)
{
  int d = threadIdx.x; // 64 threads
  float u0=0.f,u1=0.f,u2=0.f,bb=0.f;
  for (int c=0;c<64;c++){
    float w = Ws[c];
    float a = W1[c*64+d], b_ = W1[(64+c)*64+d], cw = W1[(128+c)*64+d];
    u0 += w*a; u1 += w*b_; u2 += w*cw;
    bb += bs[c]*(a+b_+cw);
  }
  bb += b1[d];
  consts[d]=u0; consts[64+d]=u1; consts[128+d]=u2; consts[192+d]=bb;
  __shared__ float rb[64];
  rb[d] = fmaxf(bb, 0.f);
  __syncthreads();
  float cA=0.f,cB=0.f,cC=0.f;
  for (int c=0;c<64;c++){
    float r = rb[c];
    cA += r*W2[c*64+d]; cB += r*W2[(64+c)*64+d]; cC += r*W2[(128+c)*64+d];
  }
  consts[256+d]=cA; consts[320+d]=cB; consts[384+d]=cC;
  // W2^T [64 d][192 c] bf16 for MFMA combine
  for (int c=0;c<192;c++) w2t[d*192 + c] = f2b(W2[c*64 + d]);
}

// ------- adj -> bf16 (A and A^T) padded to 5120, fused row/col degree sums -------
__global__ __launch_bounds__(256) void k_convT(const float* __restrict__ adj,
    u16* __restrict__ abf, u16* __restrict__ atbf,
    float* __restrict__ degr, float* __restrict__ degc)
{
  __shared__ u16 tile[64][65];
  __shared__ float cred[256];
  const int tid = threadIdx.x;
  const int c = tid & 63;
  const int wv = tid >> 6;
  const int r0 = wv * 16;
  const int bx = blockIdx.x, by = blockIdx.y;
  float cs = 0.f;
  #pragma unroll
  for (int i=0;i<16;i++){
    int r = r0 + i;
    int gm = by*64 + r, gk = bx*64 + c;
    float v = (gm < N_NODES && gk < N_NODES) ? adj[(size_t)gm*N_NODES + gk] : 0.f;
    u16 u = f2b(v);
    abf[(size_t)(by*64+r)*NP + bx*64 + c] = u;
    tile[r][c] = u;
    cs += v;
  }
  __syncthreads();
  #pragma unroll
  for (int i=0;i<16;i++){
    int r = r0 + i;
    atbf[(size_t)(bx*64+r)*NP + by*64 + c] = tile[c][r];
  }
  // row sums (bf16 tile — negligible error vs fp32)
  {
    float rs = 0.f;
    #pragma unroll
    for (int jj=0;jj<16;jj++) rs += b2f(tile[c][wv*16+jj]);
    cred[tid] = rs;
  }
  __syncthreads();
  if (tid < 64){
    float tot = cred[tid]+cred[tid+64]+cred[tid+128]+cred[tid+192];
    int gm = by*64 + tid;
    if (gm < N_NODES) atomicAdd(&degr[gm], tot);
  }
  __syncthreads();
  cred[tid] = cs;
  __syncthreads();
  if (tid < 64){
    float tot = cred[tid]+cred[tid+64]+cred[tid+128]+cred[tid+192];
    int gk = bx*64 + tid;
    if (gk < N_NODES) atomicAdd(&degc[gk], tot);
  }
}

__global__ void k_inv2(const float* __restrict__ degr, const float* __restrict__ degc,
                       float* __restrict__ invr, float* __restrict__ invc){
  int i = blockIdx.x*256 + threadIdx.x;
  if (i < NP){
    float a = degr[i], b = degc[i];
    invr[i] = (a > 0.f) ? 1.f/a : 0.f;
    invc[i] = (b > 0.f) ? 1.f/b : 0.f;
  }
}

// ---------------- x -> bf16 [128][5120] padded ----------------
__global__ void k_xbf(const float* __restrict__ x, u16* __restrict__ xbf){
  int idx = blockIdx.x*256 + threadIdx.x;
  int j = idx / NP, n = idx - j*NP;
  float v = (j < BTOT && n < N_NODES) ? x[(size_t)j*N_NODES + n] : 0.f;
  xbf[idx] = f2b(v);
}

// ------- y[n][128] += A[n][:] @ xbf^T, MFMA, K-split w/ fp32 atomics -------
__global__ __launch_bounds__(256) void k_sgemm(const u16* __restrict__ A,
    const u16* __restrict__ B, float* __restrict__ y)
{
  __shared__ __align__(16) u16 lA[128*32];
  __shared__ __align__(16) u16 lB[128*32];
  const int tid = threadIdx.x;
  const int lane = tid & 63;
  const int wv = tid >> 6;
  const int wm = (wv >> 1) * 64;
  const int wj = (wv & 1) * 64;
  const int m0 = blockIdx.x * 128;
  const int kbase = blockIdx.y * 640;
  f32x4 acc[4][4] = {};
  const int swz = (tid&3) ^ ((tid>>3)&3);
  const u16* gA = A + (size_t)(m0 + (tid>>2)) * NP + kbase + swz*8;
  const u16* gB = B + (size_t)(tid>>2) * NP + kbase + swz*8;
  char* lAb = (char*)lA + wv*1024;
  char* lBb = (char*)lB + wv*1024;
  for (int k0 = 0; k0 < 640; k0 += 32) {
    GLOAD16(gA + k0, lAb);
    GLOAD16(gA + (size_t)64*NP + k0, lAb + 4096);
    GLOAD16(gB + k0, lBb);
    GLOAD16(gB + (size_t)64*NP + k0, lBb + 4096);
    __syncthreads();
    short8 af[4], bfv[4];
    const int kb = lane >> 4;
    #pragma unroll
    for (int i=0;i<4;i++){
      int rowA = wm + i*16 + (lane&15);
      int rowB = wj + i*16 + (lane&15);
      af[i]  = *(const short8*)(lA + rowA*32 + ((kb ^ ((rowA>>1)&3))<<3));
      bfv[i] = *(const short8*)(lB + rowB*32 + ((kb ^ ((rowB>>1)&3))<<3));
    }
    #pragma unroll
    for (int i=0;i<4;i++)
      #pragma unroll
      for (int j=0;j<4;j++)
        acc[i][j] = __builtin_amdgcn_mfma_f32_16x16x32_bf16(af[i], bfv[j], acc[i][j], 0,0,0);
    __syncthreads();
  }
  #pragma unroll
  for (int i=0;i<4;i++)
    #pragma unroll
    for (int r=0;r<4;r++){
      int row = m0 + wm + i*16 + (lane>>4)*4 + r;
      #pragma unroll
      for (int j=0;j<4;j++){
        int col = wj + j*16 + (lane&15);
        atomicAdd(&y[(size_t)row*128 + col], acc[i][j][r]);
      }
    }
}

// ------- layer-1: h1t [j=bt*64+d][n] (gemm-B layout) + h1n [n][bt*64+d] -------
__global__ __launch_bounds__(256) void k_h1(const float* __restrict__ x,
    const float* __restrict__ y1, const float* __restrict__ y2,
    const float* __restrict__ invr, const float* __restrict__ invc,
    const float* __restrict__ consts, u16* __restrict__ h1t, u16* __restrict__ h1n)
{
  const int tid = threadIdx.x;
  const int n = tid & 63, d0 = (tid >> 6) * 16;
  const int n0 = blockIdx.x * 64;
  const int bt = blockIdx.y;
  const int gn = n0 + n;
  const bool valid = gn < N_NODES;
  float xv  = valid ? x[(size_t)bt*N_NODES + gn] : 0.f;
  float y1s = invr[gn] * y1[(size_t)gn*128 + bt];
  float y2s = invc[gn] * y2[(size_t)gn*128 + bt];
  u16 hb[16];
  #pragma unroll
  for (int e=0;e<16;e++){
    int d = d0 + e;
    float v = 0.f;
    if (valid)
      v = fmaxf(xv*consts[d] + y1s*consts[64+d] + y2s*consts[128+d] + consts[192+d], 0.f);
    hb[e] = f2b(v);
    h1t[(size_t)(bt*64+d)*NP + gn] = hb[e];
  }
  u16x8 p0, p1;
  #pragma unroll
  for (int e=0;e<8;e++){ p0[e]=hb[e]; p1[e]=hb[8+e]; }
  u16* dst = h1n + (size_t)gn*J_DIM + bt*64 + d0;
  *(u16x8*)dst = p0;
  *(u16x8*)(dst+8) = p1;
}

// ------- big GEMM: C[m][j] = scale[m] * sum_k A[m][k]*Bt[j][k], swizzled LDS -------
__global__ __launch_bounds__(256) void k_gemm(
    const u16* __restrict__ A, const u16* __restrict__ Bt,
    u16* __restrict__ C, const float* __restrict__ rowscale)
{
  __shared__ __align__(16) u16 lA[128*32];
  __shared__ __align__(16) u16 lB[128*32];
  const int tid = threadIdx.x;
  const int lane = tid & 63;
  const int wv = tid >> 6;
  const int wm = (wv >> 1) * 64;
  const int wj = (wv & 1) * 64;
  const int m0 = blockIdx.x * 128;
  const int j0 = blockIdx.y * 128;

  f32x4 acc[4][4] = {};
  const int swz = (tid&3) ^ ((tid>>3)&3);
  const u16* gA = A + (size_t)(m0 + (tid>>2)) * NP + swz*8;
  const u16* gB = Bt + (size_t)(j0 + (tid>>2)) * NP + swz*8;
  char* lAb = (char*)lA + wv*1024;
  char* lBb = (char*)lB + wv*1024;

  for (int k0 = 0; k0 < NP; k0 += 32) {
    GLOAD16(gA + k0, lAb);
    GLOAD16(gA + (size_t)64*NP + k0, lAb + 4096);
    GLOAD16(gB + k0, lBb);
    GLOAD16(gB + (size_t)64*NP + k0, lBb + 4096);
    __syncthreads();
    short8 af[4], bfv[4];
    const int kb = lane >> 4;
    #pragma unroll
    for (int i=0;i<4;i++){
      int rowA = wm + i*16 + (lane&15);
      int rowB = wj + i*16 + (lane&15);
      af[i]  = *(const short8*)(lA + rowA*32 + ((kb ^ ((rowA>>1)&3))<<3));
      bfv[i] = *(const short8*)(lB + rowB*32 + ((kb ^ ((rowB>>1)&3))<<3));
    }
    #pragma unroll
    for (int i=0;i<4;i++)
      #pragma unroll
      for (int j=0;j<4;j++)
        acc[i][j] = __builtin_amdgcn_mfma_f32_16x16x32_bf16(af[i], bfv[j], acc[i][j], 0,0,0);
    __syncthreads();
  }
  #pragma unroll
  for (int i=0;i<4;i++)
    #pragma unroll
    for (int r=0;r<4;r++){
      int row = m0 + wm + i*16 + (lane>>4)*4 + r;
      float sc = rowscale[row];
      #pragma unroll
      for (int j=0;j<4;j++){
        int col = j0 + wj + j*16 + (lane&15);
        C[(size_t)row*J_DIM + col] = f2b(acc[i][j][r] * sc);
      }
    }
}

// ------- layer-2 channel matmul via MFMA: hori[bt][n][d] -------
__global__ __launch_bounds__(256) void k_combine2(const u16* __restrict__ h1n,
  const u16* __restrict__ P, const u16* __restrict__ Q,
  const u16* __restrict__ w2t, const float* __restrict__ b2, u16* __restrict__ hori)
{
  const int tid = threadIdx.x;
  const int lane = tid & 63;
  const int wv = tid >> 6;
  const int n0 = blockIdx.x * 64 + wv * 16;
  const int bt = blockIdx.y;
  const int rl = lane & 15, kh = lane >> 4;

  f32x4 acc[4] = {};
  const size_t rowoff = (size_t)(n0 + rl) * J_DIM + bt*64;
  const u16* bases[3] = { h1n + rowoff, P + rowoff, Q + rowoff };
  #pragma unroll
  for (int s=0;s<3;s++){
    const u16* base = bases[s];
    #pragma unroll
    for (int kk=0;kk<2;kk++){
      short8 af = *(const short8*)(base + kk*32 + kh*8);
      #pragma unroll
      for (int j=0;j<4;j++){
        short8 bf = *(const short8*)(w2t + (j*16+rl)*192 + s*64 + kk*32 + kh*8);
        acc[j] = __builtin_amdgcn_mfma_f32_16x16x32_bf16(af, bf, acc[j], 0,0,0);
      }
    }
  }
  #pragma unroll
  for (int j=0;j<4;j++){
    int d = j*16 + rl;
    float bias = b2[d];
    #pragma unroll
    for (int r=0;r<4;r++){
      int nn = n0 + kh*4 + r;
      if (nn < N_NODES)
        hori[((size_t)bt*N_NODES + nn)*64 + d] = f2b(acc[j][r] + bias);
    }
  }
}

// ---------------- imputation head ----------------
__global__ __launch_bounds__(256) void k_head(const u16* __restrict__ hori,
  const float* __restrict__ Wf1, const float* __restrict__ bf1,
  const float* __restrict__ Wf2, const float* __restrict__ bf2, float* __restrict__ y)
{
  __shared__ float w1L[64*33];
  __shared__ float b1L[32];
  __shared__ float w2Ls[32];
  const int tid = threadIdx.x;
  for (int i = tid; i < 2048; i += 256) w1L[(i>>5)*33 + (i&31)] = Wf1[i];
  if (tid < 32){ b1L[tid] = bf1[tid]; w2Ls[tid] = Wf2[tid]; }
  __syncthreads();
  const int q = tid & 3;
  size_t pos = (size_t)blockIdx.x*64 + (tid>>2);
  const u16x8 a0 = *(const u16x8*)(hori + pos*64 + q*16);
  const u16x8 a1 = *(const u16x8*)(hori + pos*64 + q*16 + 8);
  float h[16];
  #pragma unroll
  for (int e=0;e<8;e++){ h[e]=b2f(a0[e]); h[8+e]=b2f(a1[e]); }
  float yacc = 0.f;
  #pragma unroll
  for (int jj=0; jj<32; jj++){
    float s = 0.f;
    #pragma unroll
    for (int dl=0; dl<16; dl++) s += h[dl]*w1L[(q*16+dl)*33 + jj];
    s += __shfl_xor(s, 1);
    s += __shfl_xor(s, 2);
    s += b1L[jj];
    yacc += fmaxf(s, 0.f)*w2Ls[jj];
  }
  if (q == 0) y[pos] = yacc + bf2[0];
}

// ---------------- InfoNCE loss ----------------
__global__ __launch_bounds__(256) void k_loss(const u16* __restrict__ hori,
  const int* __restrict__ missing, const int* __restrict__ posi, const int* __restrict__ negi,
  const float* __restrict__ degr, const float* __restrict__ degc,
  const float* __restrict__ consts, const float* __restrict__ b2, float* __restrict__ out)
{
  const int lane = threadIdx.x & 63;
  const int wv = threadIdx.x >> 6;
  const int wg = blockIdx.x*4 + wv;   // 0..24575
  const int m = wg & 255;
  const int bt = wg >> 8;
  const int t_ = bt % TT;
  const float cAv = consts[256+lane], cBv = consts[320+lane], cCv = consts[384+lane], b2v = b2[lane];

  int na = missing[m];
  float va = b2f(hori[((size_t)bt*N_NODES + na)*64 + lane]);
  float ss = va*va;
  #pragma unroll
  for (int o=32;o;o>>=1) ss += __shfl_xor(ss, o);
  va /= fmaxf(sqrtf(ss), 1e-8f);

  float l0 = 0.f, mx, se;
  {
    int node = posi[m];
    float v;
    if (t_ >= 4) v = b2f(hori[((size_t)bt*N_NODES + node)*64 + lane]);
    else {
      float r1 = (degr[node] > 0.f) ? 1.f : 0.f;
      float r2 = (degc[node] > 0.f) ? 1.f : 0.f;
      v = cAv + r1*cBv + r2*cCv + b2v;
    }
    float s2 = v*v;
    #pragma unroll
    for (int o=32;o;o>>=1) s2 += __shfl_xor(s2, o);
    v /= fmaxf(sqrtf(s2), 1e-8f);
    float dp = va*v;
    #pragma unroll
    for (int o=32;o;o>>=1) dp += __shfl_xor(dp, o);
    l0 = dp * 2.f;   // /TEMP, TEMP=0.5
  }
  mx = l0; se = 1.f;
  for (int k=0;k<KNEG;k++){
    int node = negi[m*KNEG + k];
    float v;
    if (t_ >= 4) v = b2f(hori[((size_t)bt*N_NODES + node)*64 + lane]);
    else {
      float r1 = (degr[node] > 0.f) ? 1.f : 0.f;
      float r2 = (degc[node] > 0.f) ? 1.f : 0.f;
      v = cAv + r1*cBv + r2*cCv + b2v;
    }
    float s2 = v*v;
    #pragma unroll
    for (int o=32;o;o>>=1) s2 += __shfl_xor(s2, o);
    v /= fmaxf(sqrtf(s2), 1e-8f);
    float dp = va*v;
    #pragma unroll
    for (int o=32;o;o>>=1) dp += __shfl_xor(dp, o);
    float lk = dp * 2.f;
    if (lk > mx){ se = se*expf(mx-lk) + 1.f; mx = lk; }
    else se += expf(lk-mx);
  }
  float term = logf(se) + mx - l0;
  __shared__ float red[4];
  if (lane == 0) red[wv] = term;
  __syncthreads();
  if (threadIdx.x == 0)
    atomicAdd(out + 480000, (red[0]+red[1]+red[2]+red[3]) * (1.f/24576.f));
}

extern "C" void kernel_launch(void* const* d_in, const int* in_sizes, int n_in,
                              void* d_out, int out_size, void* d_ws, size_t ws_size,
                              hipStream_t stream)
{
  const float* x   = (const float*)d_in[0];
  const float* adj = (const float*)d_in[1];
  const float* Ws  = (const float*)d_in[2];
  const float* bs  = (const float*)d_in[3];
  const float* W1  = (const float*)d_in[4];
  const float* b1  = (const float*)d_in[5];
  const float* W2  = (const float*)d_in[6];
  const float* b2  = (const float*)d_in[7];
  const float* Wf1 = (const float*)d_in[8];
  const float* bf1 = (const float*)d_in[9];
  const float* Wf2 = (const float*)d_in[10];
  const float* bf2 = (const float*)d_in[11];
  const int* missing = (const int*)d_in[12];
  const int* posi    = (const int*)d_in[13];
  const int* negi    = (const int*)d_in[14];
  float* out = (float*)d_out;

  char* w = (char*)d_ws;
  // fixed offsets with time-based aliasing (total ≈ 356.6 MB)
  u16* abf   = (u16*)(w + 0);                    // 52428800 B
  u16* atbf  = (u16*)(w + 52428800);             // 52428800 B
  u16* h1t   = (u16*)(w + 104857600);            // 62914560 B
  u16* h1n   = (u16*)(w + 167772160);            // 62914560 B
  u16* Pb    = (u16*)(w + 230686720);            // 62914560 B
  u16* Qb    = (u16*)(w + 293601280);            // 62914560 B
  float* degr = (float*)(w + 356515840);         // 20480 B
  float* degc = (float*)(w + 356536320);         // 20480 B
  float* invr = (float*)(w + 356556800);         // 20480 B
  float* invc = (float*)(w + 356577280);         // 20480 B
  float* consts = (float*)(w + 356597760);       // 2048 B
  u16* w2t   = (u16*)(w + 356599808);            // 24576 B
  // aliases (temporally disjoint):
  u16*   hori = (u16*)(w + 0);                   // over abf/atbf after gemms done
  u16*   xbf  = (u16*)(w + 167772160);           // over h1n before k_h1
  float* y1   = (float*)(w + 230686720);         // over Pb before k_gemm #1
  float* y2   = (float*)(w + 230686720 + 2621440);

  hipMemsetAsync(y1, 0, 2621440*2, stream);            // y accumulators
  hipMemsetAsync(degr, 0, 40960, stream);              // degr+degc (contiguous)
  hipMemsetAsync(out + 480000, 0, 4, stream);          // loss accumulator

  k_prep<<<1, 64, 0, stream>>>(Ws, bs, W1, b1, W2, consts, w2t);
  k_convT<<<dim3(80,80), 256, 0, stream>>>(adj, abf, atbf, degr, degc);
  k_inv2<<<20, 256, 0, stream>>>(degr, degc, invr, invc);
  k_xbf<<<2560, 256, 0, stream>>>(x, xbf);
  k_sgemm<<<dim3(40,8), 256, 0, stream>>>(abf, xbf, y1);
  k_sgemm<<<dim3(40,8), 256, 0, stream>>>(atbf, xbf, y2);
  k_h1<<<dim3(80,96), 256, 0, stream>>>(x, y1, y2, invr, invc, consts, h1t, h1n);
  k_gemm<<<dim3(40,48), 256, 0, stream>>>(abf, h1t, Pb, invr);
  k_gemm<<<dim3(40,48), 256, 0, stream>>>(atbf, h1t, Qb, invc);
  k_combine2<<<dim3(80,96), 256, 0, stream>>>(h1n, Pb, Qb, w2t, b2, hori);
  k_head<<<7500, 256, 0, stream>>>(hori, Wf1, bf1, Wf2, bf2, out);
  k_loss<<<6144, 256, 0, stream>>>(hori, missing, posi, negi, degr, degc, consts, b2, out);
}

// Round 3
// 886.974 us; speedup vs baseline: 2.5700x; 1.4138x over previous
//
#include <hip/hip_runtime.h>

typedef unsigned char u8;
typedef unsigned short u16;
typedef unsigned int u32;
typedef __attribute__((ext_vector_type(8))) short short8;
typedef __attribute__((ext_vector_type(8))) u16 u16x8;
typedef __attribute__((ext_vector_type(4))) float f32x4;
typedef __attribute__((ext_vector_type(4))) int i32x4;
typedef __attribute__((ext_vector_type(8))) int i32x8;

#define N_NODES 5000
#define NP 5120
#define BTOT 96
#define J_DIM 6144
#define TT 24
#define KNEG 20

__device__ __forceinline__ float b2f(u16 u){ union{u32 i; float f;} x; x.i = ((u32)u)<<16; return x.f; }
__device__ __forceinline__ u16 f2b(float f){ union{float fl; u32 i;} x; x.fl = f; u32 r = (x.i + 0x7fffu + ((x.i>>16)&1u))>>16; return (u16)r; }
__device__ __forceinline__ u8 f2e4(float f){ return (u8)(__builtin_amdgcn_cvt_pk_fp8_f32(f, 0.f, 0, false) & 0xff); }
__device__ __forceinline__ float e4tof(u8 v){
  u32 s = ((u32)(v & 0x80)) << 24;
  u32 em = v & 0x7f;
  union{u32 i; float f;} x;
  if (em >= 8) x.i = s | ((em + 0x3C0u) << 20);      // normal: (1+m/8)*2^(e-7)
  else { x.f = (float)em * 0.001953125f; x.i |= s; } // subnormal: m * 2^-9
  return x.f;
}

#define GLOAD16(g, l) __builtin_amdgcn_global_load_lds((const __attribute__((address_space(1))) void*)(g), (__attribute__((address_space(3))) void*)(l), 16, 0, 0)

// ---------------- tiny precompute: u0,u1,u2,bias1, cA,cB,cC, W2^T -----------------
__global__ void k_prep(const float* __restrict__ Ws, const float* __restrict__ bs,
                       const float* __restrict__ W1, const float* __restrict__ b1,
                       const float* __restrict__ W2, float* __restrict__ consts,
                       u16* __restrict__ w2t)
{
  int d = threadIdx.x; // 64 threads
  float u0=0.f,u1=0.f,u2=0.f,bb=0.f;
  for (int c=0;c<64;c++){
    float w = Ws[c];
    float a = W1[c*64+d], b_ = W1[(64+c)*64+d], cw = W1[(128+c)*64+d];
    u0 += w*a; u1 += w*b_; u2 += w*cw;
    bb += bs[c]*(a+b_+cw);
  }
  bb += b1[d];
  consts[d]=u0; consts[64+d]=u1; consts[128+d]=u2; consts[192+d]=bb;
  __shared__ float rb[64];
  rb[d] = fmaxf(bb, 0.f);
  __syncthreads();
  float cA=0.f,cB=0.f,cC=0.f;
  for (int c=0;c<64;c++){
    float r = rb[c];
    cA += r*W2[c*64+d]; cB += r*W2[(64+c)*64+d]; cC += r*W2[(128+c)*64+d];
  }
  consts[256+d]=cA; consts[320+d]=cB; consts[384+d]=cC;
  for (int c=0;c<192;c++) w2t[d*192 + c] = f2b(W2[c*64 + d]);
}

// ------- adj -> fp8 (A and A^T) padded to 5120, fused row/col degree sums -------
__global__ __launch_bounds__(256) void k_convT(const float* __restrict__ adj,
    u8* __restrict__ abf, u8* __restrict__ atbf,
    float* __restrict__ degr, float* __restrict__ degc)
{
  __shared__ u8 tile[64][65];
  __shared__ float cred[256];
  const int tid = threadIdx.x;
  const int c = tid & 63;
  const int wv = tid >> 6;
  const int r0 = wv * 16;
  const int bx = blockIdx.x, by = blockIdx.y;
  float cs = 0.f;
  #pragma unroll
  for (int i=0;i<16;i++){
    int r = r0 + i;
    int gm = by*64 + r, gk = bx*64 + c;
    float v = (gm < N_NODES && gk < N_NODES) ? adj[(size_t)gm*N_NODES + gk] : 0.f;
    u8 u = f2e4(v);
    abf[(size_t)(by*64+r)*NP + bx*64 + c] = u;
    tile[r][c] = u;
    cs += v;
  }
  __syncthreads();
  #pragma unroll
  for (int i=0;i<16;i++){
    int r = r0 + i;
    atbf[(size_t)(bx*64+r)*NP + by*64 + c] = tile[c][r];
  }
  // row sums from fp8 tile (0.05% relative error on deg — negligible)
  {
    float rs = 0.f;
    #pragma unroll
    for (int jj=0;jj<16;jj++) rs += e4tof(tile[c][wv*16+jj]);
    cred[tid] = rs;
  }
  __syncthreads();
  if (tid < 64){
    float tot = cred[tid]+cred[tid+64]+cred[tid+128]+cred[tid+192];
    int gm = by*64 + tid;
    if (gm < N_NODES) atomicAdd(&degr[gm], tot);
  }
  __syncthreads();
  cred[tid] = cs;
  __syncthreads();
  if (tid < 64){
    float tot = cred[tid]+cred[tid+64]+cred[tid+128]+cred[tid+192];
    int gk = bx*64 + tid;
    if (gk < N_NODES) atomicAdd(&degc[gk], tot);
  }
}

__global__ void k_inv2(const float* __restrict__ degr, const float* __restrict__ degc,
                       float* __restrict__ invr, float* __restrict__ invc){
  int i = blockIdx.x*256 + threadIdx.x;
  if (i < NP){
    float a = degr[i], b = degc[i];
    invr[i] = (a > 0.f) ? 1.f/a : 0.f;
    invc[i] = (b > 0.f) ? 1.f/b : 0.f;
  }
}

// ---------------- x -> fp8 [128][5120] padded ----------------
__global__ void k_xbf(const float* __restrict__ x, u8* __restrict__ xbf){
  int idx = blockIdx.x*256 + threadIdx.x;
  int j = idx / NP, n = idx - j*NP;
  float v = (j < BTOT && n < N_NODES) ? x[(size_t)j*N_NODES + n] : 0.f;
  xbf[idx] = f2e4(v);
}

// ======= shared fp8 MFMA tile machinery =======
// LDS tile [128 rows][128 B], 16B-chunk XOR swizzle: slot = chunk ^ (row&7).
// Staged linearly by global_load_lds from inverse-swizzled global source.
__device__ __forceinline__ i32x8 frag8(const u8* lds, int row, int kb2){
  int ba = row*128 + ((kb2 ^ (row&7))<<4);
  union { i32x8 v; i32x4 h[2]; } f;
  f.h[0] = *(const i32x4*)(lds + ba);
  f.h[1] = *(const i32x4*)(lds + (ba^16));
  return f.v;
}

// ------- y[n][128] += A(fp8)[5120x5120] @ xbf(fp8)[128x5120]^T, K-split atomics -------
__global__ __launch_bounds__(256) void k_sgemm8(const u8* __restrict__ A,
    const u8* __restrict__ B, float* __restrict__ y)
{
  __shared__ __align__(16) u8 lA[128*128];
  __shared__ __align__(16) u8 lB[128*128];
  const int tid = threadIdx.x, lane = tid & 63, wv = tid >> 6;
  const int wm = (wv >> 1) * 64, wj = (wv & 1) * 64;
  const int m0 = blockIdx.x * 128;
  const int kbase = blockIdx.y * 640;
  f32x4 acc[4][4] = {};
  const int q = tid >> 3;
  const int sc = ((tid & 7) ^ (q & 7)) << 4;
  const u8* gA = A + (size_t)(m0 + q)*NP + kbase + sc;
  const u8* gB = B + (size_t)q*NP + kbase + sc;
  for (int k0 = 0; k0 < 640; k0 += 128) {
    #pragma unroll
    for (int s=0;s<4;s++){
      GLOAD16(gA + (size_t)(s*32)*NP + k0, (char*)lA + s*4096 + wv*1024);
      GLOAD16(gB + (size_t)(s*32)*NP + k0, (char*)lB + s*4096 + wv*1024);
    }
    __syncthreads();
    i32x8 af[4], bfv[4];
    const int kb2 = (lane >> 4) * 2;
    #pragma unroll
    for (int i=0;i<4;i++){
      af[i]  = frag8(lA, wm + i*16 + (lane&15), kb2);
      bfv[i] = frag8(lB, wj + i*16 + (lane&15), kb2);
    }
    #pragma unroll
    for (int i=0;i<4;i++)
      #pragma unroll
      for (int j=0;j<4;j++)
        acc[i][j] = __builtin_amdgcn_mfma_scale_f32_16x16x128_f8f6f4(
            af[i], bfv[j], acc[i][j], 0, 0, 0, 0x7f7f7f7f, 0, 0x7f7f7f7f);
    __syncthreads();
  }
  #pragma unroll
  for (int i=0;i<4;i++)
    #pragma unroll
    for (int r=0;r<4;r++){
      int row = m0 + wm + i*16 + (lane>>4)*4 + r;
      #pragma unroll
      for (int j=0;j<4;j++){
        int col = wj + j*16 + (lane&15);
        atomicAdd(&y[(size_t)row*128 + col], acc[i][j][r]);
      }
    }
}

// ------- layer-1: h1t(fp8) [j=bt*64+d][n] + h1n(bf16) [n][bt*64+d] -------
__global__ __launch_bounds__(256) void k_h1(const float* __restrict__ x,
    const float* __restrict__ y1, const float* __restrict__ y2,
    const float* __restrict__ invr, const float* __restrict__ invc,
    const float* __restrict__ consts, u8* __restrict__ h1t, u16* __restrict__ h1n)
{
  const int tid = threadIdx.x;
  const int n = tid & 63, d0 = (tid >> 6) * 16;
  const int n0 = blockIdx.x * 64;
  const int bt = blockIdx.y;
  const int gn = n0 + n;
  const bool valid = gn < N_NODES;
  float xv  = valid ? x[(size_t)bt*N_NODES + gn] : 0.f;
  float y1s = invr[gn] * y1[(size_t)gn*128 + bt];
  float y2s = invc[gn] * y2[(size_t)gn*128 + bt];
  float hv[16];
  #pragma unroll
  for (int e=0;e<16;e++){
    int d = d0 + e;
    float v = 0.f;
    if (valid)
      v = fmaxf(xv*consts[d] + y1s*consts[64+d] + y2s*consts[128+d] + consts[192+d], 0.f);
    hv[e] = v;
    h1t[(size_t)(bt*64+d)*NP + gn] = f2e4(v);
  }
  u16x8 p0, p1;
  #pragma unroll
  for (int e=0;e<8;e++){ p0[e]=f2b(hv[e]); p1[e]=f2b(hv[8+e]); }
  u16* dst = h1n + (size_t)gn*J_DIM + bt*64 + d0;
  *(u16x8*)dst = p0;
  *(u16x8*)(dst+8) = p1;
}

// ------- big GEMM: C[m][j] = scale[m] * sum_k A[m][k]*Bt[j][k] (fp8 MX) -------
__global__ __launch_bounds__(256) void k_gemm8(
    const u8* __restrict__ A, const u8* __restrict__ Bt,
    u16* __restrict__ C, const float* __restrict__ rowscale)
{
  __shared__ __align__(16) u8 lA[128*128];
  __shared__ __align__(16) u8 lB[128*128];
  const int tid = threadIdx.x, lane = tid & 63, wv = tid >> 6;
  const int wm = (wv >> 1) * 64, wj = (wv & 1) * 64;
  const int m0 = blockIdx.x * 128;
  const int j0 = blockIdx.y * 128;
  f32x4 acc[4][4] = {};
  const int q = tid >> 3;
  const int sc = ((tid & 7) ^ (q & 7)) << 4;
  const u8* gA = A + (size_t)(m0 + q)*NP + sc;
  const u8* gB = Bt + (size_t)(j0 + q)*NP + sc;
  for (int k0 = 0; k0 < NP; k0 += 128) {
    #pragma unroll
    for (int s=0;s<4;s++){
      GLOAD16(gA + (size_t)(s*32)*NP + k0, (char*)lA + s*4096 + wv*1024);
      GLOAD16(gB + (size_t)(s*32)*NP + k0, (char*)lB + s*4096 + wv*1024);
    }
    __syncthreads();
    i32x8 af[4], bfv[4];
    const int kb2 = (lane >> 4) * 2;
    #pragma unroll
    for (int i=0;i<4;i++){
      af[i]  = frag8(lA, wm + i*16 + (lane&15), kb2);
      bfv[i] = frag8(lB, wj + i*16 + (lane&15), kb2);
    }
    #pragma unroll
    for (int i=0;i<4;i++)
      #pragma unroll
      for (int j=0;j<4;j++)
        acc[i][j] = __builtin_amdgcn_mfma_scale_f32_16x16x128_f8f6f4(
            af[i], bfv[j], acc[i][j], 0, 0, 0, 0x7f7f7f7f, 0, 0x7f7f7f7f);
    __syncthreads();
  }
  #pragma unroll
  for (int i=0;i<4;i++)
    #pragma unroll
    for (int r=0;r<4;r++){
      int row = m0 + wm + i*16 + (lane>>4)*4 + r;
      float scl = rowscale[row];
      #pragma unroll
      for (int j=0;j<4;j++){
        int col = j0 + wj + j*16 + (lane&15);
        C[(size_t)row*J_DIM + col] = f2b(acc[i][j][r] * scl);
      }
    }
}

// ------- layer-2 channel matmul via MFMA: hori[bt][n][d] -------
__global__ __launch_bounds__(256) void k_combine2(const u16* __restrict__ h1n,
  const u16* __restrict__ P, const u16* __restrict__ Q,
  const u16* __restrict__ w2t, const float* __restrict__ b2, u16* __restrict__ hori)
{
  const int tid = threadIdx.x;
  const int lane = tid & 63;
  const int wv = tid >> 6;
  const int n0 = blockIdx.x * 64 + wv * 16;
  const int bt = blockIdx.y;
  const int rl = lane & 15, kh = lane >> 4;

  f32x4 acc[4] = {};
  const size_t rowoff = (size_t)(n0 + rl) * J_DIM + bt*64;
  const u16* bases[3] = { h1n + rowoff, P + rowoff, Q + rowoff };
  #pragma unroll
  for (int s=0;s<3;s++){
    const u16* base = bases[s];
    #pragma unroll
    for (int kk=0;kk<2;kk++){
      short8 af = *(const short8*)(base + kk*32 + kh*8);
      #pragma unroll
      for (int j=0;j<4;j++){
        short8 bf = *(const short8*)(w2t + (j*16+rl)*192 + s*64 + kk*32 + kh*8);
        acc[j] = __builtin_amdgcn_mfma_f32_16x16x32_bf16(af, bf, acc[j], 0,0,0);
      }
    }
  }
  #pragma unroll
  for (int j=0;j<4;j++){
    int d = j*16 + rl;
    float bias = b2[d];
    #pragma unroll
    for (int r=0;r<4;r++){
      int nn = n0 + kh*4 + r;
      if (nn < N_NODES)
        hori[((size_t)bt*N_NODES + nn)*64 + d] = f2b(acc[j][r] + bias);
    }
  }
}

// ---------------- imputation head ----------------
__global__ __launch_bounds__(256) void k_head(const u16* __restrict__ hori,
  const float* __restrict__ Wf1, const float* __restrict__ bf1,
  const float* __restrict__ Wf2, const float* __restrict__ bf2, float* __restrict__ y)
{
  __shared__ float w1L[64*33];
  __shared__ float b1L[32];
  __shared__ float w2Ls[32];
  const int tid = threadIdx.x;
  for (int i = tid; i < 2048; i += 256) w1L[(i>>5)*33 + (i&31)] = Wf1[i];
  if (tid < 32){ b1L[tid] = bf1[tid]; w2Ls[tid] = Wf2[tid]; }
  __syncthreads();
  const int q = tid & 3;
  size_t pos = (size_t)blockIdx.x*64 + (tid>>2);
  const u16x8 a0 = *(const u16x8*)(hori + pos*64 + q*16);
  const u16x8 a1 = *(const u16x8*)(hori + pos*64 + q*16 + 8);
  float h[16];
  #pragma unroll
  for (int e=0;e<8;e++){ h[e]=b2f(a0[e]); h[8+e]=b2f(a1[e]); }
  float yacc = 0.f;
  #pragma unroll
  for (int jj=0; jj<32; jj++){
    float s = 0.f;
    #pragma unroll
    for (int dl=0; dl<16; dl++) s += h[dl]*w1L[(q*16+dl)*33 + jj];
    s += __shfl_xor(s, 1);
    s += __shfl_xor(s, 2);
    s += b1L[jj];
    yacc += fmaxf(s, 0.f)*w2Ls[jj];
  }
  if (q == 0) y[pos] = yacc + bf2[0];
}

// ---------------- InfoNCE loss ----------------
__global__ __launch_bounds__(256) void k_loss(const u16* __restrict__ hori,
  const int* __restrict__ missing, const int* __restrict__ posi, const int* __restrict__ negi,
  const float* __restrict__ degr, const float* __restrict__ degc,
  const float* __restrict__ consts, const float* __restrict__ b2, float* __restrict__ out)
{
  const int lane = threadIdx.x & 63;
  const int wv = threadIdx.x >> 6;
  const int wg = blockIdx.x*4 + wv;   // 0..24575
  const int m = wg & 255;
  const int bt = wg >> 8;
  const int t_ = bt % TT;
  const float cAv = consts[256+lane], cBv = consts[320+lane], cCv = consts[384+lane], b2v = b2[lane];

  int na = missing[m];
  float va = b2f(hori[((size_t)bt*N_NODES + na)*64 + lane]);
  float ss = va*va;
  #pragma unroll
  for (int o=32;o;o>>=1) ss += __shfl_xor(ss, o);
  va /= fmaxf(sqrtf(ss), 1e-8f);

  float l0 = 0.f, mx, se;
  {
    int node = posi[m];
    float v;
    if (t_ >= 4) v = b2f(hori[((size_t)bt*N_NODES + node)*64 + lane]);
    else {
      float r1 = (degr[node] > 0.f) ? 1.f : 0.f;
      float r2 = (degc[node] > 0.f) ? 1.f : 0.f;
      v = cAv + r1*cBv + r2*cCv + b2v;
    }
    float s2 = v*v;
    #pragma unroll
    for (int o=32;o;o>>=1) s2 += __shfl_xor(s2, o);
    v /= fmaxf(sqrtf(s2), 1e-8f);
    float dp = va*v;
    #pragma unroll
    for (int o=32;o;o>>=1) dp += __shfl_xor(dp, o);
    l0 = dp * 2.f;   // /TEMP, TEMP=0.5
  }
  mx = l0; se = 1.f;
  for (int k=0;k<KNEG;k++){
    int node = negi[m*KNEG + k];
    float v;
    if (t_ >= 4) v = b2f(hori[((size_t)bt*N_NODES + node)*64 + lane]);
    else {
      float r1 = (degr[node] > 0.f) ? 1.f : 0.f;
      float r2 = (degc[node] > 0.f) ? 1.f : 0.f;
      v = cAv + r1*cBv + r2*cCv + b2v;
    }
    float s2 = v*v;
    #pragma unroll
    for (int o=32;o;o>>=1) s2 += __shfl_xor(s2, o);
    v /= fmaxf(sqrtf(s2), 1e-8f);
    float dp = va*v;
    #pragma unroll
    for (int o=32;o;o>>=1) dp += __shfl_xor(dp, o);
    float lk = dp * 2.f;
    if (lk > mx){ se = se*expf(mx-lk) + 1.f; mx = lk; }
    else se += expf(lk-mx);
  }
  float term = logf(se) + mx - l0;
  __shared__ float red[4];
  if (lane == 0) red[wv] = term;
  __syncthreads();
  if (threadIdx.x == 0)
    atomicAdd(out + 480000, (red[0]+red[1]+red[2]+red[3]) * (1.f/24576.f));
}

extern "C" void kernel_launch(void* const* d_in, const int* in_sizes, int n_in,
                              void* d_out, int out_size, void* d_ws, size_t ws_size,
                              hipStream_t stream)
{
  const float* x   = (const float*)d_in[0];
  const float* adj = (const float*)d_in[1];
  const float* Ws  = (const float*)d_in[2];
  const float* bs  = (const float*)d_in[3];
  const float* W1  = (const float*)d_in[4];
  const float* b1  = (const float*)d_in[5];
  const float* W2  = (const float*)d_in[6];
  const float* b2  = (const float*)d_in[7];
  const float* Wf1 = (const float*)d_in[8];
  const float* bf1 = (const float*)d_in[9];
  const float* Wf2 = (const float*)d_in[10];
  const float* bf2 = (const float*)d_in[11];
  const int* missing = (const int*)d_in[12];
  const int* posi    = (const int*)d_in[13];
  const int* negi    = (const int*)d_in[14];
  float* out = (float*)d_out;

  char* w = (char*)d_ws;
  // fixed offsets (total ≈ 273.4 MB)
  u8*  abf   = (u8*) (w + 0);            // 26,214,400
  u8*  atbf  = (u8*) (w + 26214400);     // 26,214,400
  u8*  h1t   = (u8*) (w + 52428800);     // 31,457,280
  u16* h1n   = (u16*)(w + 83886080);     // 62,914,560
  u16* Pb    = (u16*)(w + 146800640);    // 62,914,560
  u16* Qb    = (u16*)(w + 209715200);    // 62,914,560
  u8*  xbf   = (u8*) (w + 272629760);    // 655,360
  float* degr = (float*)(w + 273285120); // 20480
  float* degc = (float*)(w + 273305600); // 20480
  float* invr = (float*)(w + 273326080); // 20480
  float* invc = (float*)(w + 273346560); // 20480
  float* consts = (float*)(w + 273367040); // 2048
  u16* w2t   = (u16*)(w + 273369088);    // 24576
  // aliases (temporally disjoint):
  u16*   hori = (u16*)(w + 0);           // 61.44 MB over abf/atbf/h1t-head, all dead post-gemms
  float* y1   = (float*)(w + 146800640); // over Pb, consumed by k_h1 before k_gemm8 #1
  float* y2   = (float*)(w + 146800640 + 2621440);

  hipMemsetAsync(y1, 0, 2621440*2, stream);       // y accumulators
  hipMemsetAsync(degr, 0, 40960, stream);         // degr+degc
  hipMemsetAsync(out + 480000, 0, 4, stream);     // loss accumulator

  k_prep<<<1, 64, 0, stream>>>(Ws, bs, W1, b1, W2, consts, w2t);
  k_convT<<<dim3(80,80), 256, 0, stream>>>(adj, abf, atbf, degr, degc);
  k_inv2<<<20, 256, 0, stream>>>(degr, degc, invr, invc);
  k_xbf<<<2560, 256, 0, stream>>>(x, xbf);
  k_sgemm8<<<dim3(40,8), 256, 0, stream>>>(abf, xbf, y1);
  k_sgemm8<<<dim3(40,8), 256, 0, stream>>>(atbf, xbf, y2);
  k_h1<<<dim3(80,96), 256, 0, stream>>>(x, y1, y2, invr, invc, consts, h1t, h1n);
  k_gemm8<<<dim3(40,48), 256, 0, stream>>>(abf, h1t, Pb, invr);
  k_gemm8<<<dim3(40,48), 256, 0, stream>>>(atbf, h1t, Qb, invc);
  k_combine2<<<dim3(80,96), 256, 0, stream>>>(h1n, Pb, Qb, w2t, b2, hori);
  k_head<<<7500, 256, 0, stream>>>(hori, Wf1, bf1, Wf2, bf2, out);
  k_loss<<<6144, 256, 0, stream>>>(hori, missing, posi, negi, degr, degc, consts, b2, out);
}

// Round 4
// 840.466 us; speedup vs baseline: 2.7122x; 1.0553x over previous
//
#include <hip/hip_runtime.h>

typedef unsigned char u8;
typedef unsigned short u16;
typedef unsigned int u32;
typedef __attribute__((ext_vector_type(8))) short short8;
typedef __attribute__((ext_vector_type(8))) u16 u16x8;
typedef __attribute__((ext_vector_type(4))) float f32x4;
typedef __attribute__((ext_vector_type(4))) int i32x4;
typedef __attribute__((ext_vector_type(8))) int i32x8;

#define N_NODES 5000
#define NP 5120
#define BTOT 96
#define J_DIM 6144
#define TT 24
#define KNEG 20

__device__ __forceinline__ float b2f(u16 u){ union{u32 i; float f;} x; x.i = ((u32)u)<<16; return x.f; }
__device__ __forceinline__ u16 f2b(float f){ union{float fl; u32 i;} x; x.fl = f; u32 r = (x.i + 0x7fffu + ((x.i>>16)&1u))>>16; return (u16)r; }
__device__ __forceinline__ u8 f2e4(float f){ return (u8)(__builtin_amdgcn_cvt_pk_fp8_f32(f, 0.f, 0, false) & 0xff); }
__device__ __forceinline__ float e4tof(u8 v){
  u32 s = ((u32)(v & 0x80)) << 24;
  u32 em = v & 0x7f;
  union{u32 i; float f;} x;
  if (em >= 8) x.i = s | ((em + 0x3C0u) << 20);      // normal: (1+m/8)*2^(e-7)
  else { x.f = (float)em * 0.001953125f; x.i |= s; } // subnormal: m * 2^-9
  return x.f;
}

// bank-alternating permutation (reproduces R2's measured-zero-conflict pattern)
#define GPERM(r) ((((r)>>1)&3) | (((r)&1)<<2))

#define GLOAD16(g, l) __builtin_amdgcn_global_load_lds((const __attribute__((address_space(1))) void*)(g), (__attribute__((address_space(3))) void*)(l), 16, 0, 0)

// ---------------- tiny precompute: u0,u1,u2,bias1, cA,cB,cC, W2^T -----------------
__global__ void k_prep(const float* __restrict__ Ws, const float* __restrict__ bs,
                       const float* __restrict__ W1, const float* __restrict__ b1,
                       const float* __restrict__ W2, float* __restrict__ consts,
                       u16* __restrict__ w2t)
{
  int d = threadIdx.x; // 64 threads
  float u0=0.f,u1=0.f,u2=0.f,bb=0.f;
  for (int c=0;c<64;c++){
    float w = Ws[c];
    float a = W1[c*64+d], b_ = W1[(64+c)*64+d], cw = W1[(128+c)*64+d];
    u0 += w*a; u1 += w*b_; u2 += w*cw;
    bb += bs[c]*(a+b_+cw);
  }
  bb += b1[d];
  consts[d]=u0; consts[64+d]=u1; consts[128+d]=u2; consts[192+d]=bb;
  __shared__ float rb[64];
  rb[d] = fmaxf(bb, 0.f);
  __syncthreads();
  float cA=0.f,cB=0.f,cC=0.f;
  for (int c=0;c<64;c++){
    float r = rb[c];
    cA += r*W2[c*64+d]; cB += r*W2[(64+c)*64+d]; cC += r*W2[(128+c)*64+d];
  }
  consts[256+d]=cA; consts[320+d]=cB; consts[384+d]=cC;
  for (int c=0;c<192;c++) w2t[d*192 + c] = f2b(W2[c*64 + d]);
}

// ------- adj -> fp8 (A and A^T) padded to 5120, fused row/col degree sums -------
__global__ __launch_bounds__(256) void k_convT(const float* __restrict__ adj,
    u8* __restrict__ abf, u8* __restrict__ atbf,
    float* __restrict__ degr, float* __restrict__ degc)
{
  __shared__ u8 tile[64][65];
  __shared__ float cred[256];
  const int tid = threadIdx.x;
  const int c = tid & 63;
  const int wv = tid >> 6;
  const int r0 = wv * 16;
  const int bx = blockIdx.x, by = blockIdx.y;
  float cs = 0.f;
  #pragma unroll
  for (int i=0;i<16;i++){
    int r = r0 + i;
    int gm = by*64 + r, gk = bx*64 + c;
    float v = (gm < N_NODES && gk < N_NODES) ? adj[(size_t)gm*N_NODES + gk] : 0.f;
    u8 u = f2e4(v);
    abf[(size_t)(by*64+r)*NP + bx*64 + c] = u;
    tile[r][c] = u;
    cs += v;
  }
  __syncthreads();
  #pragma unroll
  for (int i=0;i<16;i++){
    int r = r0 + i;
    atbf[(size_t)(bx*64+r)*NP + by*64 + c] = tile[c][r];
  }
  // row sums from fp8 tile (0.05% relative error on deg — negligible)
  {
    float rs = 0.f;
    #pragma unroll
    for (int jj=0;jj<16;jj++) rs += e4tof(tile[c][wv*16+jj]);
    cred[tid] = rs;
  }
  __syncthreads();
  if (tid < 64){
    float tot = cred[tid]+cred[tid+64]+cred[tid+128]+cred[tid+192];
    int gm = by*64 + tid;
    if (gm < N_NODES) atomicAdd(&degr[gm], tot);
  }
  __syncthreads();
  cred[tid] = cs;
  __syncthreads();
  if (tid < 64){
    float tot = cred[tid]+cred[tid+64]+cred[tid+128]+cred[tid+192];
    int gk = bx*64 + tid;
    if (gk < N_NODES) atomicAdd(&degc[gk], tot);
  }
}

__global__ void k_inv2(const float* __restrict__ degr, const float* __restrict__ degc,
                       float* __restrict__ invr, float* __restrict__ invc){
  int i = blockIdx.x*256 + threadIdx.x;
  if (i < NP){
    float a = degr[i], b = degc[i];
    invr[i] = (a > 0.f) ? 1.f/a : 0.f;
    invc[i] = (b > 0.f) ? 1.f/b : 0.f;
  }
}

// ---------------- x -> fp8 [128][5120] padded ----------------
__global__ void k_xbf(const float* __restrict__ x, u8* __restrict__ xbf){
  int idx = blockIdx.x*256 + threadIdx.x;
  int j = idx / NP, n = idx - j*NP;
  float v = (j < BTOT && n < N_NODES) ? x[(size_t)j*N_NODES + n] : 0.f;
  xbf[idx] = f2e4(v);
}

// ======= shared fp8 MFMA tile machinery =======
// LDS tile [128 rows][128 B], 16B-chunk swizzle: slot = chunk ^ GPERM(row&7).
// Staged linearly by global_load_lds from inverse-swizzled global source.
__device__ __forceinline__ i32x8 frag8(const u8* lds, int row, int kb2){
  int g = GPERM(row & 7);
  int ba = row*128 + ((kb2 ^ g)<<4);
  union { i32x8 v; i32x4 h[2]; } f;
  f.h[0] = *(const i32x4*)(lds + ba);
  f.h[1] = *(const i32x4*)(lds + (ba^16));
  return f.v;
}

// ------- ysl[ks][5120][128] = A(fp8) @ xbf(fp8)^T, K-sliced, no atomics -------
__global__ __launch_bounds__(256) void k_sgemm8(const u8* __restrict__ A,
    const u8* __restrict__ B, float* __restrict__ ysl)
{
  __shared__ __align__(16) u8 lA[128*128];
  __shared__ __align__(16) u8 lB[128*128];
  const int tid = threadIdx.x, lane = tid & 63, wv = tid >> 6;
  const int wm = (wv >> 1) * 64, wj = (wv & 1) * 64;
  const int m0 = blockIdx.x * 128;
  const int kbase = blockIdx.y * 640;
  f32x4 acc[4][4] = {};
  const int q = tid >> 3;
  const int sc = ((tid & 7) ^ GPERM(q & 7)) << 4;
  const u8* gA = A + (size_t)(m0 + q)*NP + kbase + sc;
  const u8* gB = B + (size_t)q*NP + kbase + sc;
  for (int k0 = 0; k0 < 640; k0 += 128) {
    #pragma unroll
    for (int s=0;s<4;s++){
      GLOAD16(gA + (size_t)(s*32)*NP + k0, (char*)lA + s*4096 + wv*1024);
      GLOAD16(gB + (size_t)(s*32)*NP + k0, (char*)lB + s*4096 + wv*1024);
    }
    __syncthreads();
    i32x8 af[4], bfv[4];
    const int kb2 = (lane >> 4) * 2;
    #pragma unroll
    for (int i=0;i<4;i++){
      af[i]  = frag8(lA, wm + i*16 + (lane&15), kb2);
      bfv[i] = frag8(lB, wj + i*16 + (lane&15), kb2);
    }
    #pragma unroll
    for (int i=0;i<4;i++)
      #pragma unroll
      for (int j=0;j<4;j++)
        acc[i][j] = __builtin_amdgcn_mfma_scale_f32_16x16x128_f8f6f4(
            af[i], bfv[j], acc[i][j], 0, 0, 0, 0x7f7f7f7f, 0, 0x7f7f7f7f);
    __syncthreads();
  }
  float* yb = ysl + (size_t)blockIdx.y * NP * 128;
  #pragma unroll
  for (int i=0;i<4;i++)
    #pragma unroll
    for (int r=0;r<4;r++){
      int row = m0 + wm + i*16 + (lane>>4)*4 + r;
      #pragma unroll
      for (int j=0;j<4;j++){
        int col = wj + j*16 + (lane&15);
        yb[(size_t)row*128 + col] = acc[i][j][r];
      }
    }
}

// ------- layer-1: h1t(fp8) [j=bt*64+d][n] + h1n(bf16) [n][bt*64+d] -------
__global__ __launch_bounds__(256) void k_h1(const float* __restrict__ x,
    const float* __restrict__ y1sl, const float* __restrict__ y2sl,
    const float* __restrict__ invr, const float* __restrict__ invc,
    const float* __restrict__ consts, u8* __restrict__ h1t, u16* __restrict__ h1n)
{
  const int tid = threadIdx.x;
  const int n = tid & 63, d0 = (tid >> 6) * 16;
  const int n0 = blockIdx.x * 64;
  const int bt = blockIdx.y;
  const int gn = n0 + n;
  const bool valid = gn < N_NODES;
  float xv  = valid ? x[(size_t)bt*N_NODES + gn] : 0.f;
  float s1 = 0.f, s2 = 0.f;
  #pragma unroll
  for (int s=0;s<8;s++){
    s1 += y1sl[((size_t)s*NP + gn)*128 + bt];
    s2 += y2sl[((size_t)s*NP + gn)*128 + bt];
  }
  float y1s = invr[gn] * s1;
  float y2s = invc[gn] * s2;
  float hv[16];
  #pragma unroll
  for (int e=0;e<16;e++){
    int d = d0 + e;
    float v = 0.f;
    if (valid)
      v = fmaxf(xv*consts[d] + y1s*consts[64+d] + y2s*consts[128+d] + consts[192+d], 0.f);
    hv[e] = v;
    h1t[(size_t)(bt*64+d)*NP + gn] = f2e4(v);
  }
  u16x8 p0, p1;
  #pragma unroll
  for (int e=0;e<8;e++){ p0[e]=f2b(hv[e]); p1[e]=f2b(hv[8+e]); }
  u16* dst = h1n + (size_t)gn*J_DIM + bt*64 + d0;
  *(u16x8*)dst = p0;
  *(u16x8*)(dst+8) = p1;
}

// ------- big GEMM: C[m][j] = scale[m] * sum_k A[m][k]*Bt[j][k] (fp8 MX) -------
__global__ __launch_bounds__(256) void k_gemm8(
    const u8* __restrict__ A, const u8* __restrict__ Bt,
    u16* __restrict__ C, const float* __restrict__ rowscale)
{
  __shared__ __align__(16) u8 lA[128*128];
  __shared__ __align__(16) u8 lB[128*128];
  const int tid = threadIdx.x, lane = tid & 63, wv = tid >> 6;
  const int wm = (wv >> 1) * 64, wj = (wv & 1) * 64;
  const int m0 = blockIdx.x * 128;
  const int j0 = blockIdx.y * 128;
  f32x4 acc[4][4] = {};
  const int q = tid >> 3;
  const int sc = ((tid & 7) ^ GPERM(q & 7)) << 4;
  const u8* gA = A + (size_t)(m0 + q)*NP + sc;
  const u8* gB = Bt + (size_t)(j0 + q)*NP + sc;
  for (int k0 = 0; k0 < NP; k0 += 128) {
    #pragma unroll
    for (int s=0;s<4;s++){
      GLOAD16(gA + (size_t)(s*32)*NP + k0, (char*)lA + s*4096 + wv*1024);
      GLOAD16(gB + (size_t)(s*32)*NP + k0, (char*)lB + s*4096 + wv*1024);
    }
    __syncthreads();
    i32x8 af[4], bfv[4];
    const int kb2 = (lane >> 4) * 2;
    #pragma unroll
    for (int i=0;i<4;i++){
      af[i]  = frag8(lA, wm + i*16 + (lane&15), kb2);
      bfv[i] = frag8(lB, wj + i*16 + (lane&15), kb2);
    }
    #pragma unroll
    for (int i=0;i<4;i++)
      #pragma unroll
      for (int j=0;j<4;j++)
        acc[i][j] = __builtin_amdgcn_mfma_scale_f32_16x16x128_f8f6f4(
            af[i], bfv[j], acc[i][j], 0, 0, 0, 0x7f7f7f7f, 0, 0x7f7f7f7f);
    __syncthreads();
  }
  #pragma unroll
  for (int i=0;i<4;i++)
    #pragma unroll
    for (int r=0;r<4;r++){
      int row = m0 + wm + i*16 + (lane>>4)*4 + r;
      float scl = rowscale[row];
      #pragma unroll
      for (int j=0;j<4;j++){
        int col = j0 + wj + j*16 + (lane&15);
        C[(size_t)row*J_DIM + col] = f2b(acc[i][j][r] * scl);
      }
    }
}

// ------- fused layer-2 channel matmul + imputation head -------
__global__ __launch_bounds__(256) void k_comb(const u16* __restrict__ h1n,
  const u16* __restrict__ P, const u16* __restrict__ Q,
  const u16* __restrict__ w2t, const float* __restrict__ b2,
  const float* __restrict__ Wf1, const float* __restrict__ bf1,
  const float* __restrict__ Wf2, const float* __restrict__ bf2,
  u16* __restrict__ hori, float* __restrict__ yout)
{
  __shared__ float w1L[64*33];
  __shared__ float hT[64][65];
  __shared__ float b1L[32], w2Ls[32];
  const int tid = threadIdx.x;
  for (int i = tid; i < 2048; i += 256) w1L[(i>>5)*33 + (i&31)] = Wf1[i];
  if (tid < 32){ b1L[tid] = bf1[tid]; w2Ls[tid] = Wf2[tid]; }
  const int lane = tid & 63;
  const int wv = tid >> 6;
  const int n0 = blockIdx.x * 64 + wv * 16;
  const int bt = blockIdx.y;
  const int rl = lane & 15, kh = lane >> 4;

  f32x4 acc[4] = {};
  const size_t rowoff = (size_t)(n0 + rl) * J_DIM + bt*64;
  const u16* bases[3] = { h1n + rowoff, P + rowoff, Q + rowoff };
  #pragma unroll
  for (int s=0;s<3;s++){
    const u16* base = bases[s];
    #pragma unroll
    for (int kk=0;kk<2;kk++){
      short8 af = *(const short8*)(base + kk*32 + kh*8);
      #pragma unroll
      for (int j=0;j<4;j++){
        short8 bf = *(const short8*)(w2t + (j*16+rl)*192 + s*64 + kk*32 + kh*8);
        acc[j] = __builtin_amdgcn_mfma_f32_16x16x32_bf16(af, bf, acc[j], 0,0,0);
      }
    }
  }
  #pragma unroll
  for (int j=0;j<4;j++){
    int d = j*16 + rl;
    float bias = b2[d];
    #pragma unroll
    for (int r=0;r<4;r++){
      float hv = acc[j][r] + bias;
      int nn = n0 + kh*4 + r;
      hT[wv*16 + kh*4 + r][d] = hv;
      if (nn < N_NODES)
        hori[((size_t)bt*N_NODES + nn)*64 + d] = f2b(hv);
    }
  }
  __syncthreads();
  // head phase: thread (node = tid>>2, q = tid&3)
  const int q = tid & 3, node = tid >> 2;
  float h[16];
  #pragma unroll
  for (int e=0;e<16;e++) h[e] = hT[node][q*16 + e];
  float yacc = 0.f;
  #pragma unroll
  for (int jj=0; jj<32; jj++){
    float s = 0.f;
    #pragma unroll
    for (int dl=0; dl<16; dl++) s += h[dl]*w1L[(q*16+dl)*33 + jj];
    s += __shfl_xor(s, 1);
    s += __shfl_xor(s, 2);
    s += b1L[jj];
    yacc += fmaxf(s, 0.f)*w2Ls[jj];
  }
  int gn = blockIdx.x*64 + node;
  if (q == 0 && gn < N_NODES)
    yout[(size_t)bt*N_NODES + gn] = yacc + bf2[0];
}

// ---------------- InfoNCE loss ----------------
__global__ __launch_bounds__(256) void k_loss(const u16* __restrict__ hori,
  const int* __restrict__ missing, const int* __restrict__ posi, const int* __restrict__ negi,
  const float* __restrict__ degr, const float* __restrict__ degc,
  const float* __restrict__ consts, const float* __restrict__ b2, float* __restrict__ out)
{
  const int lane = threadIdx.x & 63;
  const int wv = threadIdx.x >> 6;
  const int wg = blockIdx.x*4 + wv;   // 0..24575
  const int m = wg & 255;
  const int bt = wg >> 8;
  const int t_ = bt % TT;
  const float cAv = consts[256+lane], cBv = consts[320+lane], cCv = consts[384+lane], b2v = b2[lane];

  int na = missing[m];
  float va = b2f(hori[((size_t)bt*N_NODES + na)*64 + lane]);
  float ss = va*va;
  #pragma unroll
  for (int o=32;o;o>>=1) ss += __shfl_xor(ss, o);
  va /= fmaxf(sqrtf(ss), 1e-8f);

  float l0 = 0.f, mx, se;
  {
    int node = posi[m];
    float v;
    if (t_ >= 4) v = b2f(hori[((size_t)bt*N_NODES + node)*64 + lane]);
    else {
      float r1 = (degr[node] > 0.f) ? 1.f : 0.f;
      float r2 = (degc[node] > 0.f) ? 1.f : 0.f;
      v = cAv + r1*cBv + r2*cCv + b2v;
    }
    float s2 = v*v;
    #pragma unroll
    for (int o=32;o;o>>=1) s2 += __shfl_xor(s2, o);
    v /= fmaxf(sqrtf(s2), 1e-8f);
    float dp = va*v;
    #pragma unroll
    for (int o=32;o;o>>=1) dp += __shfl_xor(dp, o);
    l0 = dp * 2.f;   // /TEMP, TEMP=0.5
  }
  mx = l0; se = 1.f;
  for (int k=0;k<KNEG;k++){
    int node = negi[m*KNEG + k];
    float v;
    if (t_ >= 4) v = b2f(hori[((size_t)bt*N_NODES + node)*64 + lane]);
    else {
      float r1 = (degr[node] > 0.f) ? 1.f : 0.f;
      float r2 = (degc[node] > 0.f) ? 1.f : 0.f;
      v = cAv + r1*cBv + r2*cCv + b2v;
    }
    float s2 = v*v;
    #pragma unroll
    for (int o=32;o;o>>=1) s2 += __shfl_xor(s2, o);
    v /= fmaxf(sqrtf(s2), 1e-8f);
    float dp = va*v;
    #pragma unroll
    for (int o=32;o;o>>=1) dp += __shfl_xor(dp, o);
    float lk = dp * 2.f;
    if (lk > mx){ se = se*expf(mx-lk) + 1.f; mx = lk; }
    else se += expf(lk-mx);
  }
  float term = logf(se) + mx - l0;
  __shared__ float red[4];
  if (lane == 0) red[wv] = term;
  __syncthreads();
  if (threadIdx.x == 0)
    atomicAdd(out + 480000, (red[0]+red[1]+red[2]+red[3]) * (1.f/24576.f));
}

extern "C" void kernel_launch(void* const* d_in, const int* in_sizes, int n_in,
                              void* d_out, int out_size, void* d_ws, size_t ws_size,
                              hipStream_t stream)
{
  const float* x   = (const float*)d_in[0];
  const float* adj = (const float*)d_in[1];
  const float* Ws  = (const float*)d_in[2];
  const float* bs  = (const float*)d_in[3];
  const float* W1  = (const float*)d_in[4];
  const float* b1  = (const float*)d_in[5];
  const float* W2  = (const float*)d_in[6];
  const float* b2  = (const float*)d_in[7];
  const float* Wf1 = (const float*)d_in[8];
  const float* bf1 = (const float*)d_in[9];
  const float* Wf2 = (const float*)d_in[10];
  const float* bf2 = (const float*)d_in[11];
  const int* missing = (const int*)d_in[12];
  const int* posi    = (const int*)d_in[13];
  const int* negi    = (const int*)d_in[14];
  float* out = (float*)d_out;

  char* w = (char*)d_ws;
  // fixed offsets (total ≈ 273.4 MB)
  u8*  abf   = (u8*) (w + 0);            // 26,214,400
  u8*  atbf  = (u8*) (w + 26214400);     // 26,214,400
  u8*  h1t   = (u8*) (w + 52428800);     // 31,457,280
  u16* h1n   = (u16*)(w + 83886080);     // 62,914,560
  u16* Pb    = (u16*)(w + 146800640);    // 62,914,560
  u16* Qb    = (u16*)(w + 209715200);    // 62,914,560
  u8*  xbf   = (u8*) (w + 272629760);    // 655,360
  float* degr = (float*)(w + 273285120); // 20480
  float* degc = (float*)(w + 273305600); // 20480
  float* invr = (float*)(w + 273326080); // 20480
  float* invc = (float*)(w + 273346560); // 20480
  float* consts = (float*)(w + 273367040); // 2048
  u16* w2t   = (u16*)(w + 273369088);    // 24576
  // aliases (temporally disjoint):
  u16*   hori  = (u16*)(w + 0);           // over abf/atbf (dead post-gemms)
  float* y1sl  = (float*)(w + 146800640); // 8 slices x 5120 x 128 f32 = 20,971,520 (over Pb)
  float* y2sl  = (float*)(w + 167772160); // 20,971,520 (over Pb tail; consumed before k_gemm8)

  hipMemsetAsync(degr, 0, 40960, stream);         // degr+degc
  hipMemsetAsync(out + 480000, 0, 4, stream);     // loss accumulator

  k_prep<<<1, 64, 0, stream>>>(Ws, bs, W1, b1, W2, consts, w2t);
  k_convT<<<dim3(80,80), 256, 0, stream>>>(adj, abf, atbf, degr, degc);
  k_inv2<<<20, 256, 0, stream>>>(degr, degc, invr, invc);
  k_xbf<<<2560, 256, 0, stream>>>(x, xbf);
  k_sgemm8<<<dim3(40,8), 256, 0, stream>>>(abf, xbf, y1sl);
  k_sgemm8<<<dim3(40,8), 256, 0, stream>>>(atbf, xbf, y2sl);
  k_h1<<<dim3(80,96), 256, 0, stream>>>(x, y1sl, y2sl, invr, invc, consts, h1t, h1n);
  k_gemm8<<<dim3(40,48), 256, 0, stream>>>(abf, h1t, Pb, invr);
  k_gemm8<<<dim3(40,48), 256, 0, stream>>>(atbf, h1t, Qb, invc);
  k_comb<<<dim3(80,96), 256, 0, stream>>>(h1n, Pb, Qb, w2t, b2, Wf1, bf1, Wf2, bf2, hori, out);
  k_loss<<<6144, 256, 0, stream>>>(hori, missing, posi, negi, degr, degc, consts, b2, out);
}